// Round 9
// baseline (268.700 us; speedup 1.0000x reference)
//
#include <hip/hip_runtime.h>
#include <hip/hip_bf16.h>
#include <stdint.h>

#define BM 128
#define BN 128
#define BK 64

typedef __attribute__((ext_vector_type(8))) short    bf16x8;  // 8×16-bit = 4 VGPR (MFMA A/B frag)
typedef __attribute__((ext_vector_type(8))) _Float16 f16x8;
typedef __attribute__((ext_vector_type(4))) float    f32x4;   // MFMA acc

typedef __attribute__((address_space(1))) void GV;            // global
typedef __attribute__((address_space(3))) void LV;            // LDS

__device__ __forceinline__ unsigned short f2bf(float f){
  union { float f; unsigned u; } x; x.f = f;
  unsigned r = x.u + 0x7fffu + ((x.u >> 16) & 1u);            // RNE
  return (unsigned short)(r >> 16);
}
__device__ __forceinline__ float bf2f(unsigned short h){
  union { unsigned u; float f; } x; x.u = ((unsigned)h) << 16; return x.f;
}
__device__ __forceinline__ unsigned short f2h(float f){
  union { _Float16 h; unsigned short u; } c; c.h = (_Float16)f; return c.u;  // RNE
}

template<bool F16>
__device__ __forceinline__ void mma16(f32x4& acc, bf16x8 a, bf16x8 b){
  if constexpr (F16)
    acc = __builtin_amdgcn_mfma_f32_16x16x32_f16(__builtin_bit_cast(f16x8, a),
                                                 __builtin_bit_cast(f16x8, b), acc, 0, 0, 0);
  else
    acc = __builtin_amdgcn_mfma_f32_16x16x32_bf16(a, b, acc, 0, 0, 0);
}

// Raw s_barrier bracketed by zero-instruction compiler memory fences: stops
// loads/stores from migrating across the barrier (needed since we drop the
// lgkm asm) WITHOUT sched_barrier order-pinning (m141: pinning costs ~40%).
#define SBAR() { asm volatile("" ::: "memory"); __builtin_amdgcn_s_barrier(); asm volatile("" ::: "memory"); }

// ============== 128² 2-phase core (verified; used by k_scores / k_projQK) ==============
__device__ __forceinline__ bf16x8 frag_ld(const unsigned short* lds, int r, int k){
  int byte = ((r << 7) + (k << 1)) ^ ((r & 7) << 4);
  return *(const bf16x8*)((const char*)lds + byte);
}

__device__ __forceinline__ void stage_tile(const unsigned short* __restrict__ src, int ld,
                                           unsigned short* lds, int tid){
  #pragma unroll
  for (int t = 0; t < 4; ++t){
    int idx = t*256 + tid;
    int row = idx >> 3;
    int kc  = (idx & 7) ^ (row & 7);
    const unsigned short* g = src + (size_t)row*ld + kc*8;
    __builtin_amdgcn_global_load_lds((GV*)g, (LV*)(lds + idx*8), 16, 0, 0);
  }
}

template<bool F16>
__device__ __forceinline__ void gemm_core(const unsigned short* __restrict__ At,
                                          const unsigned short* __restrict__ Bt,
                                          int lda, int ldb, int nkt,
                                          unsigned short* lsA, unsigned short* lsB,
                                          f32x4 (&acc)[4][4]){
  const int tid  = threadIdx.x;
  const int lane = tid & 63;
  const int wr = ((tid >> 7) & 1) << 6;
  const int wc = ((tid >> 6) & 1) << 6;
  const int l15 = lane & 15, lg = lane >> 4;

  for (int kt = 0; kt < nkt; ++kt){
    stage_tile(At + (size_t)kt*BK, lda, lsA, tid);
    stage_tile(Bt + (size_t)kt*BK, ldb, lsB, tid);
    __syncthreads();
    #pragma unroll
    for (int kk = 0; kk < 2; ++kk){
      bf16x8 af[4], bfr[4];
      #pragma unroll
      for (int mf = 0; mf < 4; ++mf) af[mf]  = frag_ld(lsA, wr + mf*16 + l15, kk*32 + lg*8);
      #pragma unroll
      for (int nf = 0; nf < 4; ++nf) bfr[nf] = frag_ld(lsB, wc + nf*16 + l15, kk*32 + lg*8);
      #pragma unroll
      for (int mf = 0; mf < 4; ++mf)
        #pragma unroll
        for (int nf = 0; nf < 4; ++nf)
          mma16<F16>(acc[mf][nf], af[mf], bfr[nf]);
    }
    __syncthreads();
  }
}

#define ZERO_ACC4(acc) { _Pragma("unroll") for (int i_=0;i_<4;++i_) _Pragma("unroll") for (int j_=0;j_<4;++j_) acc[i_][j_] = (f32x4){0.f,0.f,0.f,0.f}; }

// ============== 256² READ-AHEAD core (k_projV / k_pv8) ==============
// LDS (128KB): Abuf0 @0, Abuf1 @32KB, Bbuf0 @64KB, Bbuf1 @96KB.
// Row-major [256][64] 16-bit tiles, swizzle byte ^= (row&7)<<4 (pre-swizzled global
// source + swizzled ds_read address; linear LDS dest — rule #21). kk offsets INSIDE
// the XOR; only row-multiple offsets (BUF*32768, mf*2048) are additive.
//
// ROUND-9: ds_reads issue ONE PHASE EARLY (doubled frag regs afX/afY, bfr0/bfr1),
// NO hand lgkm gates (compiler emits counted waits — m97/G7), ONE barrier per
// phase. Region between barriers = [MFMA_p ; reads_{p+1} ; stage] so matrix-pipe
// drain overlaps the LDS burst. Buffer cert: vmcnt(0) at P3-end (drains A(t+1)
// issued >=2 phases back + B(t+1) from prev P4) -> P4 may read buf^1.
// Stage-write hazards: every write is >=1 barrier after the last competing
// read's forced completion (reads complete before the MFMA that uses them).
// MFMA order identical to rounds 2-8 -> bit-identical output.

__device__ __forceinline__ void stg2(const unsigned short* g, size_t qq, unsigned short* d){
  __builtin_amdgcn_global_load_lds((GV*)g, (LV*)d, 16, 0, 0);
  __builtin_amdgcn_global_load_lds((GV*)(g + qq), (LV*)(d + 4096), 16, 0, 0);
}

template<bool F16, int BUF>
__device__ __forceinline__ void ktile_ra(int t, int nkt,
    const unsigned short*& gA0, const unsigned short*& gA1,
    const unsigned short*& gB0, const unsigned short*& gB1,
    size_t qA, size_t qB,
    unsigned short* dA, unsigned short* dB,
    const char* lA_k0, const char* lA_k1, const char* lB_k0, const char* lB_k1,
    bf16x8 (&afX)[4], bf16x8 (&afY)[4], bf16x8 (&bfr0)[4], bf16x8 (&bfr1)[4],
    f32x4 (&acc)[8][4]){
  // entering: afX = A(kk0,mf0-3)@BUF, bfr0 = B(kk0)@BUF  [loaded in prev P4 region]

  // ---- P1 region prep: read afY (A kk0 mf4-7) for P2; stage A(t+1) h0 -> Abuf^1
  #pragma unroll
  for (int i = 0; i < 4; ++i) afY[i] = *(const bf16x8*)(lA_k0 + BUF*32768 + (4+i)*2048);
  if (t + 1 < nkt) stg2(gA0 + 64, qA, dA + (BUF^1)*16384);
  SBAR();
  __builtin_amdgcn_s_setprio(1);
  #pragma unroll
  for (int mf = 0; mf < 4; ++mf)
    #pragma unroll
    for (int nf = 0; nf < 4; ++nf) mma16<F16>(acc[mf][nf], afX[mf], bfr0[nf]);   // MFMA1
  __builtin_amdgcn_s_setprio(0);

  // ---- P2 region prep (same region as MFMA1): read afX (A kk1 mf0-3) + bfr1 (B kk1); stage A(t+1) h1
  #pragma unroll
  for (int i = 0; i < 4; ++i) afX[i]  = *(const bf16x8*)(lA_k1 + BUF*32768 + i*2048);
  #pragma unroll
  for (int i = 0; i < 4; ++i) bfr1[i] = *(const bf16x8*)(lB_k1 + BUF*32768 + i*2048);
  if (t + 1 < nkt) stg2(gA1 + 64, qA, dA + (BUF^1)*16384 + 8192);
  SBAR();
  __builtin_amdgcn_s_setprio(1);
  #pragma unroll
  for (int mf = 0; mf < 4; ++mf)
    #pragma unroll
    for (int nf = 0; nf < 4; ++nf) mma16<F16>(acc[mf+4][nf], afY[mf], bfr0[nf]); // MFMA2
  __builtin_amdgcn_s_setprio(0);

  // ---- P3 region prep: read afY (A kk1 mf4-7); certify tile t+1 (cheap: all old)
  #pragma unroll
  for (int i = 0; i < 4; ++i) afY[i] = *(const bf16x8*)(lA_k1 + BUF*32768 + (4+i)*2048);
  asm volatile("s_waitcnt vmcnt(0)" ::: "memory");
  SBAR();
  __builtin_amdgcn_s_setprio(1);
  #pragma unroll
  for (int mf = 0; mf < 4; ++mf)
    #pragma unroll
    for (int nf = 0; nf < 4; ++nf) mma16<F16>(acc[mf][nf], afX[mf], bfr1[nf]);   // MFMA3
  __builtin_amdgcn_s_setprio(0);

  // ---- P4 region prep: read NEXT tile's afX + bfr0 from buf^1 (certified above);
  //      stage B(t+2) -> Bbuf(BUF) (its last reads completed before MFMA3)
  if (t + 1 < nkt){
    #pragma unroll
    for (int i = 0; i < 4; ++i) afX[i]  = *(const bf16x8*)(lA_k0 + (BUF^1)*32768 + i*2048);
    #pragma unroll
    for (int i = 0; i < 4; ++i) bfr0[i] = *(const bf16x8*)(lB_k0 + (BUF^1)*32768 + i*2048);
    if (t + 2 < nkt){
      stg2(gB0 + 128, qB, dB + BUF*16384);
      stg2(gB1 + 128, qB, dB + BUF*16384 + 8192);
    }
  }
  SBAR();
  __builtin_amdgcn_s_setprio(1);
  #pragma unroll
  for (int mf = 0; mf < 4; ++mf)
    #pragma unroll
    for (int nf = 0; nf < 4; ++nf) mma16<F16>(acc[mf+4][nf], afY[mf], bfr1[nf]); // MFMA4
  __builtin_amdgcn_s_setprio(0);

  gA0 += 64; gA1 += 64; gB0 += 64; gB1 += 64;          // advance to next K-tile
}

template<bool F16>
__device__ __forceinline__ void gemm256(const unsigned short* __restrict__ Ab, int lda,
                                        const unsigned short* __restrict__ Bb, int ldb,
                                        int nkt, unsigned short* sm, f32x4 (&acc)[8][4]){
  const int tid  = threadIdx.x;
  const int lane = tid & 63, l15 = lane & 15, lg = lane >> 4;
  const int wid  = tid >> 6;
  const int wrow0 = (wid >> 2) << 7;     // 0 / 128
  const int wcol0 = (wid & 3) << 6;      // 0 / 64 / 128 / 192

  // staging pointers (computed once, bumped per K-tile)
  const int srow = tid >> 3;                          // 0..63
  const int scol = ((tid & 7) ^ (srow & 7)) << 3;     // pre-swizzled chunk
  const unsigned short* gA0 = Ab + (size_t)srow*lda + scol;
  const unsigned short* gA1 = gA0 + (size_t)128*lda;
  const unsigned short* gB0 = Bb + (size_t)srow*ldb + scol;
  const unsigned short* gB1 = gB0 + (size_t)128*ldb;
  const size_t qA = (size_t)64*lda, qB = (size_t)64*ldb;
  unsigned short* dA = sm + tid*8;                    // linear LDS dests
  unsigned short* dB = sm + 32768 + tid*8;

  // LDS read byte-bases: kk offset INSIDE the XOR; mf/BUF offsets row-multiple.
  const int mswz = (l15 & 7) << 4;
  const char* smc = (const char*)sm;
  const char* lA_k0 = smc + ((wrow0 + l15) << 7) + (((lg << 4))      ^ mswz);
  const char* lA_k1 = smc + ((wrow0 + l15) << 7) + ((64 + (lg << 4)) ^ mswz);
  const char* lB_k0 = smc + 65536 + ((wcol0 + l15) << 7) + (((lg << 4))      ^ mswz);
  const char* lB_k1 = smc + 65536 + ((wcol0 + l15) << 7) + ((64 + (lg << 4)) ^ mswz);

  bf16x8 afX[4], afY[4], bfr0[4], bfr1[4];

  // prologue: A(0) h0+h1 -> Abuf0, B(0) -> Bbuf0, B(1) -> Bbuf1
  stg2(gA0, qA, dA);          stg2(gA1, qA, dA + 8192);
  stg2(gB0, qB, dB);          stg2(gB1, qB, dB + 8192);
  stg2(gB0 + 64, qB, dB + 16384);
  stg2(gB1 + 64, qB, dB + 16384 + 8192);
  asm volatile("s_waitcnt vmcnt(4)" ::: "memory");    // tile 0 fully landed; B(1) in flight
  SBAR();
  // preload P1(0) operands (compiler inserts the lgkm wait before MFMA1)
  #pragma unroll
  for (int i = 0; i < 4; ++i) afX[i]  = *(const bf16x8*)(lA_k0 + i*2048);
  #pragma unroll
  for (int i = 0; i < 4; ++i) bfr0[i] = *(const bf16x8*)(lB_k0 + i*2048);

  for (int t = 0; t < nkt; t += 2){
    ktile_ra<F16,0>(t,   nkt, gA0,gA1,gB0,gB1,qA,qB,dA,dB,
                    lA_k0,lA_k1,lB_k0,lB_k1, afX,afY,bfr0,bfr1, acc);
    ktile_ra<F16,1>(t+1, nkt, gA0,gA1,gB0,gB1,qA,qB,dA,dB,
                    lA_k0,lA_k1,lB_k0,lB_k1, afX,afY,bfr0,bfr1, acc);
  }
}

#define ZERO_ACC8(acc) { _Pragma("unroll") for (int i_=0;i_<8;++i_) _Pragma("unroll") for (int j_=0;j_<4;++j_) acc[i_][j_] = (f32x4){0.f,0.f,0.f,0.f}; }

// ================= converts =================
__global__ __launch_bounds__(256) void k_cvt_x(const float* __restrict__ x,
                                               unsigned short* __restrict__ xh, int n4){
  int i = blockIdx.x*blockDim.x + threadIdx.x;
  int stride = gridDim.x*blockDim.x;
  for (; i < n4; i += stride){
    float4 v = ((const float4*)x)[i];
    ushort4 o; o.x = f2h(v.x); o.y = f2h(v.y); o.z = f2h(v.z); o.w = f2h(v.w);
    ((ushort4*)xh)[i] = o;
  }
}

__global__ __launch_bounds__(256) void k_cvt_wt(const float* __restrict__ Wq, const float* __restrict__ Wk,
                                                const float* __restrict__ Wv, unsigned short* __restrict__ Wt){
  int n = blockIdx.x*32 + threadIdx.x;
  int k = blockIdx.y*8  + threadIdx.y;
  float v;
  if (n < 128)      v = Wq[(size_t)k*128  + n];
  else if (n < 256) v = Wk[(size_t)k*128  + (n-128)];
  else              v = Wv[(size_t)k*1024 + (n-256)];
  Wt[(size_t)n*1024 + k] = f2h(v);
}

// ================= Q/K projection: 128² 2-phase core, grid (128,2) = 256 blocks =================
__global__ __launch_bounds__(256) void k_projQK(const unsigned short* __restrict__ xh,
                                                const unsigned short* __restrict__ Wt,
                                                const float* __restrict__ bq, const float* __restrict__ bk,
                                                unsigned short* __restrict__ Qh, unsigned short* __restrict__ Kh){
  __shared__ unsigned short lsA[BM*BK], lsB[BN*BK];
  const int m0  = blockIdx.x * BM;
  const int sel = blockIdx.y;                // 0 = Q, 1 = K
  f32x4 acc[4][4]; ZERO_ACC4(acc);
  gemm_core<true>(xh + (size_t)m0*1024, Wt + (size_t)sel*128*1024, 1024, 1024, 16, lsA, lsB, acc);

  const int tid = threadIdx.x, lane = tid & 63;
  const int wr = ((tid >> 7) & 1) << 6;
  const int wc = ((tid >> 6) & 1) << 6;
  const int l15 = lane & 15, lg = lane >> 4;

  unsigned short* T  = sel ? Kh : Qh;
  const float* bias  = sel ? bk : bq;
  #pragma unroll
  for (int mf = 0; mf < 4; ++mf){
    #pragma unroll
    for (int nf = 0; nf < 4; ++nf){
      int c = wc + nf*16 + l15;
      float bi = bias[c];
      #pragma unroll
      for (int r = 0; r < 4; ++r){
        int gr = m0 + wr + mf*16 + lg*4 + r;
        T[(size_t)gr*128 + c] = f2h(acc[mf][nf][r] + bi);
      }
    }
  }
}

// ================= V projection: read-ahead 256² core, grid 64M x 4N = 256 blocks =================
__global__ __launch_bounds__(512, 2) void k_projV(const unsigned short* __restrict__ xh,
                                                  const unsigned short* __restrict__ Wt,
                                                  const float* __restrict__ bv,
                                                  unsigned short* __restrict__ Vt){
  extern __shared__ unsigned short sm[];
  const int bid = blockIdx.x;
  const int m0 = (bid & 63) << 8;            // 0..16128
  const int n0 = (bid >> 6) << 8;            // 0..768 (V column block)

  f32x4 acc[8][4]; ZERO_ACC8(acc);
  gemm256<true>(xh + (size_t)m0*1024, 1024,
                Wt + (size_t)(256 + n0)*1024, 1024, 16, sm, acc);

  const int tid = threadIdx.x, lane = tid & 63, l15 = lane & 15, lg = lane >> 4;
  const int wid = tid >> 6;
  const int wrow0 = (wid >> 2) << 7;
  const int wcol0 = (wid & 3) << 6;

  #pragma unroll
  for (int mf = 0; mf < 8; ++mf){
    int gr0 = m0 + wrow0 + mf*16 + lg*4;     // 4 consecutive seq rows
    int b = gr0 >> 11, t0 = gr0 & 2047;
    #pragma unroll
    for (int nf = 0; nf < 4; ++nf){
      int j = n0 + wcol0 + nf*16 + l15;      // 0..1023
      float bi = bv[j];
      ushort4 pk;
      pk.x = f2bf(acc[mf][nf][0] + bi);
      pk.y = f2bf(acc[mf][nf][1] + bi);
      pk.z = f2bf(acc[mf][nf][2] + bi);
      pk.w = f2bf(acc[mf][nf][3] + bi);
      *(ushort4*)(Vt + ((size_t)b*1024 + j)*2048 + t0) = pk;
    }
  }
}

// ================= scores: P = exp(QK^T) bf16 + row-sum atomics (128² core) =================
__global__ __launch_bounds__(256) void k_scores(const unsigned short* __restrict__ Qh,
                                                const unsigned short* __restrict__ Kh,
                                                unsigned short* __restrict__ P, float* __restrict__ lsum){
  __shared__ unsigned short lsA[BM*BK], lsB[BN*BK];
  const int s0 = blockIdx.x * BM;
  const int t0 = blockIdx.y * BN;
  const int b  = blockIdx.z;
  f32x4 acc[4][4]; ZERO_ACC4(acc);
  gemm_core<true>(Qh + ((size_t)b*2048 + s0)*128, Kh + ((size_t)b*2048 + t0)*128, 128, 128, 2, lsA, lsB, acc);

  unsigned short* Pb = P + (size_t)b*2048*2048;
  float* lb = lsum + b*2048;
  const int tid = threadIdx.x, lane = tid & 63;
  const int wr = ((tid >> 7) & 1) << 6;
  const int wc = ((tid >> 6) & 1) << 6;
  const int l15 = lane & 15, lg = lane >> 4;

  #pragma unroll
  for (int mf = 0; mf < 4; ++mf){
    #pragma unroll
    for (int r = 0; r < 4; ++r){
      int sr = s0 + wr + mf*16 + lg*4 + r;
      float rsum = 0.f;
      #pragma unroll
      for (int nf = 0; nf < 4; ++nf){
        float e = __expf(acc[mf][nf][r]);
        unsigned short h = f2bf(e);
        int tc = t0 + wc + nf*16 + l15;
        Pb[(size_t)sr*2048 + tc] = h;
        rsum += bf2f(h);
      }
      #pragma unroll
      for (int d = 1; d < 16; d <<= 1) rsum += __shfl_xor(rsum, d);
      if (l15 == 0) atomicAdd(&lb[sr], rsum);
    }
  }
}

// ================= PV: read-ahead 256² core, grid 256 (batch = bid&7 -> XCD) =================
__global__ __launch_bounds__(512, 2) void k_pv8(const unsigned short* __restrict__ P,
                                                const unsigned short* __restrict__ Vt,
                                                const float* __restrict__ lsum,
                                                float* __restrict__ out){
  extern __shared__ unsigned short sm[];
  const int bid = blockIdx.x;
  const int b   = bid & 7;
  const int r2  = bid >> 3;
  const int s0  = (r2 >> 2) << 8;
  const int j0  = (r2 & 3) << 8;

  f32x4 acc[8][4]; ZERO_ACC8(acc);
  gemm256<false>(P  + ((size_t)b*2048 + s0)*2048, 2048,
                 Vt + ((size_t)b*1024 + j0)*2048, 2048, 32, sm, acc);

  const int tid = threadIdx.x, lane = tid & 63, l15 = lane & 15, lg = lane >> 4;
  const int wid = tid >> 6;
  const int wrow0 = (wid >> 2) << 7;
  const int wcol0 = (wid & 3) << 6;

  const float* lb = lsum + b*2048;
  float* ob = out + (size_t)b*2048*1024;
  #pragma unroll
  for (int mf = 0; mf < 8; ++mf){
    #pragma unroll
    for (int r = 0; r < 4; ++r){
      int sr = s0 + wrow0 + mf*16 + lg*4 + r;
      float rl = 1.0f / lb[sr];
      #pragma unroll
      for (int nf = 0; nf < 4; ++nf){
        int jc = j0 + wcol0 + nf*16 + l15;
        float v = acc[mf][nf][r] * rl;
        ob[(size_t)sr*1024 + jc] = 1.0f - 2.0f/(1.0f + __expf(2.0f*v));
      }
    }
  }
}

extern "C" void kernel_launch(void* const* d_in, const int* in_sizes, int n_in,
                              void* d_out, int out_size, void* d_ws, size_t ws_size,
                              hipStream_t stream){
  const float* x  = (const float*)d_in[0];
  const float* Wq = (const float*)d_in[1];
  const float* bq = (const float*)d_in[2];
  const float* Wk = (const float*)d_in[3];
  const float* bk = (const float*)d_in[4];
  const float* Wv = (const float*)d_in[5];
  const float* bv = (const float*)d_in[6];
  float* out = (float*)d_out;

  char* ws = (char*)d_ws;
  const size_t MB = 1024*1024;
  unsigned short* Wt   = (unsigned short*)(ws);            // [1280][1024] fp16
  unsigned short* Qh   = (unsigned short*)(ws + 4*MB);     // [16384][128] fp16
  unsigned short* Kh   = (unsigned short*)(ws + 8*MB);
  unsigned short* Vt   = (unsigned short*)(ws + 12*MB);    // [8][1024][2048] bf16
  unsigned short* P    = (unsigned short*)(ws + 44*MB);    // [8][2048][2048] bf16
  float*          lsum = (float*)(ws + 108*MB);            // [8][2048] f32
  unsigned short* xh   = (unsigned short*)d_out;           // scratch: x fp16 in out buf

  hipMemsetAsync(lsum, 0, 16384*sizeof(float), stream);
  k_cvt_x  <<<2048, 256, 0, stream>>>(x, xh, 16384*1024/4);
  k_cvt_wt <<<dim3(40,128), dim3(32,8), 0, stream>>>(Wq, Wk, Wv, Wt);
  k_projQK <<<dim3(128,2), 256, 0, stream>>>(xh, Wt, bq, bk, Qh, Kh);
  k_projV  <<<256, 512, 131072, stream>>>(xh, Wt, bv, Vt);
  k_scores <<<dim3(16,16,8), 256, 0, stream>>>(Qh, Kh, P, lsum);
  k_pv8    <<<256, 512, 131072, stream>>>(P, Vt, lsum, out);
}

// Round 10
// 195.897 us; speedup vs baseline: 1.3716x; 1.3716x over previous
//
#include <hip/hip_runtime.h>
#include <hip/hip_bf16.h>
#include <stdint.h>

#define BM 128
#define BN 128
#define BK 64

typedef __attribute__((ext_vector_type(8))) short    bf16x8;  // 8×16-bit = 4 VGPR (MFMA A/B frag)
typedef __attribute__((ext_vector_type(8))) _Float16 f16x8;
typedef __attribute__((ext_vector_type(4))) float    f32x4;   // MFMA acc

typedef __attribute__((address_space(1))) void GV;            // global
typedef __attribute__((address_space(3))) void LV;            // LDS

__device__ __forceinline__ unsigned short f2bf(float f){
  union { float f; unsigned u; } x; x.f = f;
  unsigned r = x.u + 0x7fffu + ((x.u >> 16) & 1u);            // RNE
  return (unsigned short)(r >> 16);
}
__device__ __forceinline__ float bf2f(unsigned short h){
  union { unsigned u; float f; } x; x.u = ((unsigned)h) << 16; return x.f;
}
__device__ __forceinline__ unsigned short f2h(float f){
  union { _Float16 h; unsigned short u; } c; c.h = (_Float16)f; return c.u;  // RNE
}

template<bool F16>
__device__ __forceinline__ void mma16(f32x4& acc, bf16x8 a, bf16x8 b){
  if constexpr (F16)
    acc = __builtin_amdgcn_mfma_f32_16x16x32_f16(__builtin_bit_cast(f16x8, a),
                                                 __builtin_bit_cast(f16x8, b), acc, 0, 0, 0);
  else
    acc = __builtin_amdgcn_mfma_f32_16x16x32_bf16(a, b, acc, 0, 0, 0);
}

// r8-verified barrier/wait forms (lockstep schedule is the measured best of 4 variants)
#define SBAR()  __builtin_amdgcn_s_barrier()
#define LGKM0() asm volatile("s_waitcnt lgkmcnt(0)" ::: "memory")

// ============== 128² 2-phase core (verified; used by k_scores) ==============
__device__ __forceinline__ bf16x8 frag_ld(const unsigned short* lds, int r, int k){
  int byte = ((r << 7) + (k << 1)) ^ ((r & 7) << 4);
  return *(const bf16x8*)((const char*)lds + byte);
}

__device__ __forceinline__ void stage_tile(const unsigned short* __restrict__ src, int ld,
                                           unsigned short* lds, int tid){
  #pragma unroll
  for (int t = 0; t < 4; ++t){
    int idx = t*256 + tid;
    int row = idx >> 3;
    int kc  = (idx & 7) ^ (row & 7);
    const unsigned short* g = src + (size_t)row*ld + kc*8;
    __builtin_amdgcn_global_load_lds((GV*)g, (LV*)(lds + idx*8), 16, 0, 0);
  }
}

template<bool F16>
__device__ __forceinline__ void gemm_core(const unsigned short* __restrict__ At,
                                          const unsigned short* __restrict__ Bt,
                                          int lda, int ldb, int nkt,
                                          unsigned short* lsA, unsigned short* lsB,
                                          f32x4 (&acc)[4][4]){
  const int tid  = threadIdx.x;
  const int lane = tid & 63;
  const int wr = ((tid >> 7) & 1) << 6;
  const int wc = ((tid >> 6) & 1) << 6;
  const int l15 = lane & 15, lg = lane >> 4;

  for (int kt = 0; kt < nkt; ++kt){
    stage_tile(At + (size_t)kt*BK, lda, lsA, tid);
    stage_tile(Bt + (size_t)kt*BK, ldb, lsB, tid);
    __syncthreads();
    #pragma unroll
    for (int kk = 0; kk < 2; ++kk){
      bf16x8 af[4], bfr[4];
      #pragma unroll
      for (int mf = 0; mf < 4; ++mf) af[mf]  = frag_ld(lsA, wr + mf*16 + l15, kk*32 + lg*8);
      #pragma unroll
      for (int nf = 0; nf < 4; ++nf) bfr[nf] = frag_ld(lsB, wc + nf*16 + l15, kk*32 + lg*8);
      #pragma unroll
      for (int mf = 0; mf < 4; ++mf)
        #pragma unroll
        for (int nf = 0; nf < 4; ++nf)
          mma16<F16>(acc[mf][nf], af[mf], bfr[nf]);
    }
    __syncthreads();
  }
}

#define ZERO_ACC4(acc) { _Pragma("unroll") for (int i_=0;i_<4;++i_) _Pragma("unroll") for (int j_=0;j_<4;++j_) acc[i_][j_] = (f32x4){0.f,0.f,0.f,0.f}; }

// ============== 256² 4-phase core (r8 lockstep schedule — verified 199.8 µs total) ==============
__device__ __forceinline__ void stg2(const unsigned short* g, size_t qq, unsigned short* d){
  __builtin_amdgcn_global_load_lds((GV*)g, (LV*)d, 16, 0, 0);
  __builtin_amdgcn_global_load_lds((GV*)(g + qq), (LV*)(d + 4096), 16, 0, 0);
}

template<bool F16, int BUF>
__device__ __forceinline__ void ktile256(int t, int nkt,
    const unsigned short*& gA0, const unsigned short*& gA1,
    const unsigned short*& gB0, const unsigned short*& gB1,
    size_t qA, size_t qB,
    unsigned short* dA, unsigned short* dB,
    const char* lA_k0, const char* lA_k1, const char* lB_k0, const char* lB_k1,
    f32x4 (&acc)[8][4]){
  bf16x8 af[4], bfr[4];

  // ---- P1: A kk0 mf0-3 + B kk0; stage A(t+1) h0 -> other buf
  #pragma unroll
  for (int i = 0; i < 4; ++i) af[i]  = *(const bf16x8*)(lA_k0 + BUF*32768 + i*2048);
  #pragma unroll
  for (int i = 0; i < 4; ++i) bfr[i] = *(const bf16x8*)(lB_k0 + BUF*32768 + i*2048);
  if (t + 1 < nkt) stg2(gA0 + 64, qA, dA + (BUF^1)*16384);
  SBAR(); LGKM0();
  __builtin_amdgcn_s_setprio(1);
  #pragma unroll
  for (int mf = 0; mf < 4; ++mf)
    #pragma unroll
    for (int nf = 0; nf < 4; ++nf) mma16<F16>(acc[mf][nf], af[mf], bfr[nf]);
  __builtin_amdgcn_s_setprio(0);
  SBAR();

  // ---- P2: A kk0 mf4-7 (reuse B); stage A(t+1) h1
  #pragma unroll
  for (int i = 0; i < 4; ++i) af[i] = *(const bf16x8*)(lA_k0 + BUF*32768 + (4+i)*2048);
  if (t + 1 < nkt) stg2(gA1 + 64, qA, dA + (BUF^1)*16384 + 8192);
  SBAR(); LGKM0();
  __builtin_amdgcn_s_setprio(1);
  #pragma unroll
  for (int mf = 0; mf < 4; ++mf)
    #pragma unroll
    for (int nf = 0; nf < 4; ++nf) mma16<F16>(acc[mf+4][nf], af[mf], bfr[nf]);
  __builtin_amdgcn_s_setprio(0);
  SBAR();

  // ---- P3: A kk1 mf0-3 + B kk1; stage B(t+2) h0 (half-tile granularity)
  #pragma unroll
  for (int i = 0; i < 4; ++i) af[i]  = *(const bf16x8*)(lA_k1 + BUF*32768 + i*2048);
  #pragma unroll
  for (int i = 0; i < 4; ++i) bfr[i] = *(const bf16x8*)(lB_k1 + BUF*32768 + i*2048);
  if (t + 2 < nkt) stg2(gB0 + 128, qB, dB + BUF*16384);
  SBAR(); LGKM0();
  __builtin_amdgcn_s_setprio(1);
  #pragma unroll
  for (int mf = 0; mf < 4; ++mf)
    #pragma unroll
    for (int nf = 0; nf < 4; ++nf) mma16<F16>(acc[mf][nf], af[mf], bfr[nf]);
  __builtin_amdgcn_s_setprio(0);
  SBAR();

  // ---- P4: A kk1 mf4-7; stage B(t+2) h1; counted vmcnt (leave B(t+2)'s 4 in flight)
  #pragma unroll
  for (int i = 0; i < 4; ++i) af[i] = *(const bf16x8*)(lA_k1 + BUF*32768 + (4+i)*2048);
  if (t + 2 < nkt){
    stg2(gB1 + 128, qB, dB + BUF*16384 + 8192);
    asm volatile("s_waitcnt vmcnt(4)" ::: "memory");   // tile t+1 landed; B(t+2) in flight
  } else if (t + 1 < nkt){
    asm volatile("s_waitcnt vmcnt(0)" ::: "memory");   // tail: drain A(t+1)
  }
  SBAR(); LGKM0();
  __builtin_amdgcn_s_setprio(1);
  #pragma unroll
  for (int mf = 0; mf < 4; ++mf)
    #pragma unroll
    for (int nf = 0; nf < 4; ++nf) mma16<F16>(acc[mf+4][nf], af[mf], bfr[nf]);
  __builtin_amdgcn_s_setprio(0);
  SBAR();

  gA0 += 64; gA1 += 64; gB0 += 64; gB1 += 64;          // advance to next K-tile
}

template<bool F16>
__device__ __forceinline__ void gemm256(const unsigned short* __restrict__ Ab, int lda,
                                        const unsigned short* __restrict__ Bb, int ldb,
                                        int nkt, unsigned short* sm, f32x4 (&acc)[8][4]){
  const int tid  = threadIdx.x;
  const int lane = tid & 63, l15 = lane & 15, lg = lane >> 4;
  const int wid  = tid >> 6;
  const int wrow0 = (wid >> 2) << 7;     // 0 / 128
  const int wcol0 = (wid & 3) << 6;      // 0 / 64 / 128 / 192

  const int srow = tid >> 3;                          // 0..63
  const int scol = ((tid & 7) ^ (srow & 7)) << 3;     // pre-swizzled chunk
  const unsigned short* gA0 = Ab + (size_t)srow*lda + scol;
  const unsigned short* gA1 = gA0 + (size_t)128*lda;
  const unsigned short* gB0 = Bb + (size_t)srow*ldb + scol;
  const unsigned short* gB1 = gB0 + (size_t)128*ldb;
  const size_t qA = (size_t)64*lda, qB = (size_t)64*ldb;
  unsigned short* dA = sm + tid*8;                    // linear LDS dests
  unsigned short* dB = sm + 32768 + tid*8;

  const int mswz = (l15 & 7) << 4;
  const char* smc = (const char*)sm;
  const char* lA_k0 = smc + ((wrow0 + l15) << 7) + (((lg << 4))      ^ mswz);
  const char* lA_k1 = smc + ((wrow0 + l15) << 7) + ((64 + (lg << 4)) ^ mswz);
  const char* lB_k0 = smc + 65536 + ((wcol0 + l15) << 7) + (((lg << 4))      ^ mswz);
  const char* lB_k1 = smc + 65536 + ((wcol0 + l15) << 7) + ((64 + (lg << 4)) ^ mswz);

  // prologue: A(0) h0+h1 -> Abuf0, B(0) -> Bbuf0, B(1) -> Bbuf1
  stg2(gA0, qA, dA);          stg2(gA1, qA, dA + 8192);
  stg2(gB0, qB, dB);          stg2(gB1, qB, dB + 8192);
  stg2(gB0 + 64, qB, dB + 16384);
  stg2(gB1 + 64, qB, dB + 16384 + 8192);
  asm volatile("s_waitcnt vmcnt(4)" ::: "memory");    // tile 0 fully landed
  SBAR();

  for (int t = 0; t < nkt; t += 2){
    ktile256<F16,0>(t,   nkt, gA0,gA1,gB0,gB1,qA,qB,dA,dB,lA_k0,lA_k1,lB_k0,lB_k1,acc);
    ktile256<F16,1>(t+1, nkt, gA0,gA1,gB0,gB1,qA,qB,dA,dB,lA_k0,lA_k1,lB_k0,lB_k1,acc);
  }
}

#define ZERO_ACC8(acc) { _Pragma("unroll") for (int i_=0;i_<8;++i_) _Pragma("unroll") for (int j_=0;j_<4;++j_) acc[i_][j_] = (f32x4){0.f,0.f,0.f,0.f}; }

// ================= W transpose+convert (kept: tiny, scattered reads once) =================
__global__ __launch_bounds__(256) void k_cvt_wt(const float* __restrict__ Wq, const float* __restrict__ Wk,
                                                const float* __restrict__ Wv, unsigned short* __restrict__ Wt){
  int n = blockIdx.x*32 + threadIdx.x;
  int k = blockIdx.y*8  + threadIdx.y;
  float v;
  if (n < 128)      v = Wq[(size_t)k*128  + n];
  else if (n < 256) v = Wk[(size_t)k*128  + (n-128)];
  else              v = Wv[(size_t)k*1024 + (n-256)];
  Wt[(size_t)n*1024 + k] = f2h(v);
}

// ================= Q/K projection + FUSED x->fp16 convert =================
// A-path reg-staged from fp32 x (f2h -> ds_write_b128, same swizzled layout as
// stage_tile would produce). sel==0 blocks additionally store the fp16 panel to
// xh for k_projV (read in the NEXT kernel - stream-ordered, no intra-grid race;
// sel==1 re-reads x fp32, L3-hot). Eliminates the standalone k_cvt_x dispatch.
__global__ __launch_bounds__(256) void k_projQK(const float* __restrict__ x,
                                                const unsigned short* __restrict__ Wt,
                                                const float* __restrict__ bq, const float* __restrict__ bk,
                                                unsigned short* __restrict__ Qh, unsigned short* __restrict__ Kh,
                                                unsigned short* __restrict__ xh){
  __shared__ unsigned short lsA[BM*BK], lsB[BN*BK];
  const int m0  = blockIdx.x * BM;
  const int sel = blockIdx.y;                // 0 = Q, 1 = K
  const int tid = threadIdx.x, lane = tid & 63;
  const int wr = ((tid >> 7) & 1) << 6;
  const int wc = ((tid >> 6) & 1) << 6;
  const int l15 = lane & 15, lg = lane >> 4;

  f32x4 acc[4][4]; ZERO_ACC4(acc);

  for (int kt = 0; kt < 16; ++kt){
    // B (weights) via global_load_lds as before
    stage_tile(Wt + (size_t)sel*128*1024 + (size_t)kt*BK, 1024, lsB, tid);
    // A (x rows) reg-staged: fp32 -> fp16 -> LDS (identical layout), sel0 also -> xh
    #pragma unroll
    for (int t = 0; t < 4; ++t){
      int idx = t*256 + tid;
      int row = idx >> 3;
      int kc  = (idx & 7) ^ (row & 7);
      const float* gx = x + (size_t)(m0 + row)*1024 + kt*64 + kc*8;
      float4 v0 = *(const float4*)gx;
      float4 v1 = *(const float4*)(gx + 4);
      bf16x8 pk;
      pk[0] = (short)f2h(v0.x); pk[1] = (short)f2h(v0.y);
      pk[2] = (short)f2h(v0.z); pk[3] = (short)f2h(v0.w);
      pk[4] = (short)f2h(v1.x); pk[5] = (short)f2h(v1.y);
      pk[6] = (short)f2h(v1.z); pk[7] = (short)f2h(v1.w);
      *(bf16x8*)(lsA + idx*8) = pk;
      if (sel == 0) *(bf16x8*)(xh + (size_t)(m0 + row)*1024 + kt*64 + kc*8) = pk;
    }
    __syncthreads();
    #pragma unroll
    for (int kk = 0; kk < 2; ++kk){
      bf16x8 af[4], bfr[4];
      #pragma unroll
      for (int mf = 0; mf < 4; ++mf) af[mf]  = frag_ld(lsA, wr + mf*16 + l15, kk*32 + lg*8);
      #pragma unroll
      for (int nf = 0; nf < 4; ++nf) bfr[nf] = frag_ld(lsB, wc + nf*16 + l15, kk*32 + lg*8);
      #pragma unroll
      for (int mf = 0; mf < 4; ++mf)
        #pragma unroll
        for (int nf = 0; nf < 4; ++nf)
          mma16<true>(acc[mf][nf], af[mf], bfr[nf]);
    }
    __syncthreads();
  }

  unsigned short* T  = sel ? Kh : Qh;
  const float* bias  = sel ? bk : bq;
  #pragma unroll
  for (int mf = 0; mf < 4; ++mf){
    #pragma unroll
    for (int nf = 0; nf < 4; ++nf){
      int c = wc + nf*16 + l15;
      float bi = bias[c];
      #pragma unroll
      for (int r = 0; r < 4; ++r){
        int gr = m0 + wr + mf*16 + lg*4 + r;
        T[(size_t)gr*128 + c] = f2h(acc[mf][nf][r] + bi);
      }
    }
  }
}

// ================= V projection: 256² core, grid 64M x 4N = 256 blocks (one pass) =================
__global__ __launch_bounds__(512, 2) void k_projV(const unsigned short* __restrict__ xh,
                                                  const unsigned short* __restrict__ Wt,
                                                  const float* __restrict__ bv,
                                                  unsigned short* __restrict__ Vt){
  extern __shared__ unsigned short sm[];
  const int bid = blockIdx.x;
  const int m0 = (bid & 63) << 8;            // 0..16128
  const int n0 = (bid >> 6) << 8;            // 0..768 (V column block)

  f32x4 acc[8][4]; ZERO_ACC8(acc);
  gemm256<true>(xh + (size_t)m0*1024, 1024,
                Wt + (size_t)(256 + n0)*1024, 1024, 16, sm, acc);

  const int tid = threadIdx.x, lane = tid & 63, l15 = lane & 15, lg = lane >> 4;
  const int wid = tid >> 6;
  const int wrow0 = (wid >> 2) << 7;
  const int wcol0 = (wid & 3) << 6;

  #pragma unroll
  for (int mf = 0; mf < 8; ++mf){
    int gr0 = m0 + wrow0 + mf*16 + lg*4;     // 4 consecutive seq rows
    int b = gr0 >> 11, t0 = gr0 & 2047;
    #pragma unroll
    for (int nf = 0; nf < 4; ++nf){
      int j = n0 + wcol0 + nf*16 + l15;      // 0..1023
      float bi = bv[j];
      ushort4 pk;
      pk.x = f2bf(acc[mf][nf][0] + bi);
      pk.y = f2bf(acc[mf][nf][1] + bi);
      pk.z = f2bf(acc[mf][nf][2] + bi);
      pk.w = f2bf(acc[mf][nf][3] + bi);
      *(ushort4*)(Vt + ((size_t)b*1024 + j)*2048 + t0) = pk;
    }
  }
}

// ================= scores: P = exp(QK^T) bf16 + row-sum atomics (128² core) =================
__global__ __launch_bounds__(256) void k_scores(const unsigned short* __restrict__ Qh,
                                                const unsigned short* __restrict__ Kh,
                                                unsigned short* __restrict__ P, float* __restrict__ lsum){
  __shared__ unsigned short lsA[BM*BK], lsB[BN*BK];
  const int s0 = blockIdx.x * BM;
  const int t0 = blockIdx.y * BN;
  const int b  = blockIdx.z;
  f32x4 acc[4][4]; ZERO_ACC4(acc);
  gemm_core<true>(Qh + ((size_t)b*2048 + s0)*128, Kh + ((size_t)b*2048 + t0)*128, 128, 128, 2, lsA, lsB, acc);

  unsigned short* Pb = P + (size_t)b*2048*2048;
  float* lb = lsum + b*2048;
  const int tid = threadIdx.x, lane = tid & 63;
  const int wr = ((tid >> 7) & 1) << 6;
  const int wc = ((tid >> 6) & 1) << 6;
  const int l15 = lane & 15, lg = lane >> 4;

  #pragma unroll
  for (int mf = 0; mf < 4; ++mf){
    #pragma unroll
    for (int r = 0; r < 4; ++r){
      int sr = s0 + wr + mf*16 + lg*4 + r;
      float rsum = 0.f;
      #pragma unroll
      for (int nf = 0; nf < 4; ++nf){
        float e = __expf(acc[mf][nf][r]);
        unsigned short h = f2bf(e);
        int tc = t0 + wc + nf*16 + l15;
        Pb[(size_t)sr*2048 + tc] = h;
        rsum += bf2f(h);
      }
      #pragma unroll
      for (int d = 1; d < 16; d <<= 1) rsum += __shfl_xor(rsum, d);
      if (l15 == 0) atomicAdd(&lb[sr], rsum);
    }
  }
}

// ================= PV: 256² core, grid 256 (batch = bid&7 -> XCD) =================
__global__ __launch_bounds__(512, 2) void k_pv8(const unsigned short* __restrict__ P,
                                                const unsigned short* __restrict__ Vt,
                                                const float* __restrict__ lsum,
                                                float* __restrict__ out){
  extern __shared__ unsigned short sm[];
  const int bid = blockIdx.x;
  const int b   = bid & 7;
  const int r2  = bid >> 3;
  const int s0  = (r2 >> 2) << 8;
  const int j0  = (r2 & 3) << 8;

  f32x4 acc[8][4]; ZERO_ACC8(acc);
  gemm256<false>(P  + ((size_t)b*2048 + s0)*2048, 2048,
                 Vt + ((size_t)b*1024 + j0)*2048, 2048, 32, sm, acc);

  const int tid = threadIdx.x, lane = tid & 63, l15 = lane & 15, lg = lane >> 4;
  const int wid = tid >> 6;
  const int wrow0 = (wid >> 2) << 7;
  const int wcol0 = (wid & 3) << 6;

  const float* lb = lsum + b*2048;
  float* ob = out + (size_t)b*2048*1024;
  #pragma unroll
  for (int mf = 0; mf < 8; ++mf){
    #pragma unroll
    for (int r = 0; r < 4; ++r){
      int sr = s0 + wrow0 + mf*16 + lg*4 + r;
      float rl = 1.0f / lb[sr];
      #pragma unroll
      for (int nf = 0; nf < 4; ++nf){
        int jc = j0 + wcol0 + nf*16 + l15;
        float v = acc[mf][nf][r] * rl;
        ob[(size_t)sr*1024 + jc] = 1.0f - 2.0f/(1.0f + __expf(2.0f*v));
      }
    }
  }
}

extern "C" void kernel_launch(void* const* d_in, const int* in_sizes, int n_in,
                              void* d_out, int out_size, void* d_ws, size_t ws_size,
                              hipStream_t stream){
  const float* x  = (const float*)d_in[0];
  const float* Wq = (const float*)d_in[1];
  const float* bq = (const float*)d_in[2];
  const float* Wk = (const float*)d_in[3];
  const float* bk = (const float*)d_in[4];
  const float* Wv = (const float*)d_in[5];
  const float* bv = (const float*)d_in[6];
  float* out = (float*)d_out;

  char* ws = (char*)d_ws;
  const size_t MB = 1024*1024;
  unsigned short* Wt   = (unsigned short*)(ws);            // [1280][1024] fp16
  unsigned short* Qh   = (unsigned short*)(ws + 4*MB);     // [16384][128] fp16
  unsigned short* Kh   = (unsigned short*)(ws + 8*MB);
  unsigned short* Vt   = (unsigned short*)(ws + 12*MB);    // [8][1024][2048] bf16
  unsigned short* P    = (unsigned short*)(ws + 44*MB);    // [8][2048][2048] bf16
  float*          lsum = (float*)(ws + 108*MB);            // [8][2048] f32
  unsigned short* xh   = (unsigned short*)d_out;           // scratch: x fp16 in out buf (written by k_projQK sel0)

  hipMemsetAsync(lsum, 0, 16384*sizeof(float), stream);
  k_cvt_wt <<<dim3(40,128), dim3(32,8), 0, stream>>>(Wq, Wk, Wv, Wt);
  k_projQK <<<dim3(128,2), 256, 0, stream>>>(x, Wt, bq, bk, Qh, Kh, xh);
  k_projV  <<<256, 512, 131072, stream>>>(xh, Wt, bv, Vt);
  k_scores <<<dim3(16,16,8), 256, 0, stream>>>(Qh, Kh, P, lsum);
  k_pv8    <<<256, 512, 131072, stream>>>(P, Vt, lsum, out);
}